// Round 8
// baseline (107.877 us; speedup 1.0000x reference)
//
#include <hip/hip_runtime.h>

typedef unsigned short u16;
typedef __attribute__((ext_vector_type(4))) float f32x4;
typedef __attribute__((ext_vector_type(8))) short s16x8;

#define BM 128
#define BN 128
#define BK 32

__device__ inline float bf2f(u16 u) {
    unsigned v = ((unsigned)u) << 16;
    return __builtin_bit_cast(float, v);
}
__device__ inline u16 f2bf(float f) {
    unsigned u = __builtin_bit_cast(unsigned, f);
    unsigned r = (u + 0x7FFFu + ((u >> 16) & 1u)) >> 16;
    return (u16)r;
}

typedef const __attribute__((address_space(1))) void* gptr_t;
typedef __attribute__((address_space(3))) void* lptr_t;
__device__ inline void gload16(const u16* gp, u16* lp) {
    __builtin_amdgcn_global_load_lds((gptr_t)gp, (lptr_t)lp, 16, 0, 0);
}

// ---------------- fused_pre: transpose + weight permutes + rowoff + biases ----------------
__global__ __launch_bounds__(256) void fused_pre(
    const float* __restrict__ x, const int* __restrict__ idx,
    const float* __restrict__ stem_w,
    const float* __restrict__ cls_conv_w, const float* __restrict__ cls_conv_b,
    const float* __restrict__ reg_conv_w, const float* __restrict__ reg_conv_b,
    const float* __restrict__ cls_pred_w, const float* __restrict__ cls_pred_b,
    const float* __restrict__ reg_pred_w, const float* __restrict__ reg_pred_b,
    const float* __restrict__ obj_pred_w, const float* __restrict__ obj_pred_b,
    u16* __restrict__ xT, u16* __restrict__ Wsb, u16* __restrict__ Wc,
    u16* __restrict__ Wf, int* __restrict__ rowoff,
    float* __restrict__ bc, float* __restrict__ bp, u16* __restrict__ zpage) {
    __shared__ u16 tile[64 * 258];
    const int blk = blockIdx.x;
    const int t = threadIdx.x;

    if (blk < 800) {                       // ---- transpose ----
        int b = blk / 100, hw0 = (blk % 100) * 64;
        int l = t & 63, w = t >> 6;
        const float* xb = x + (size_t)b * 256 * 6400 + hw0 + l;
#pragma unroll 4
        for (int k = 0; k < 64; ++k) {
            int c = w + k * 4;
            tile[l * 258 + c] = f2bf(xb[(size_t)c * 6400]);
        }
        __syncthreads();
        u16* outb = xT + ((size_t)b * 6400 + hw0) * 256;
#pragma unroll
        for (int i = 0; i < 8; ++i) {
            int hw = w * 16 + i * 2 + (l >> 5);
            int c = (l & 31) * 8;
            *(int4*)(outb + (size_t)hw * 256 + c) = *(const int4*)&tile[hw * 258 + c];
        }
    } else if (blk < 1312) {               // ---- Wc permute ----
        int o = blk - 800;
        const float* src = (o < 256) ? (cls_conv_w + (size_t)o * 2304)
                                     : (reg_conv_w + (size_t)(o - 256) * 2304);
        u16* dst = Wc + (size_t)o * 2304;
#pragma unroll
        for (int it = 0; it < 9; ++it) {
            int kk = it * 256 + t;
            int j = kk >> 8, c = kk & 255;
            dst[kk] = f2bf(src[c * 9 + j]);
        }
    } else if (blk < 1888) {               // ---- rowoff ----
        int i = (blk - 1312) * 256 + t;
        int n = i / 9, j = i % 9;
        int b = idx[n * 3 + 0], y = idx[n * 3 + 1], xx0 = idx[n * 3 + 2];
        int yy = y + j / 3 - 1;
        int xx = xx0 + j % 3 - 1;
        rowoff[i] = ((unsigned)yy < 80u && (unsigned)xx < 80u)
                        ? (b * 6400 + yy * 80 + xx) * 256 : -1;
    } else if (blk < 1952) {               // ---- Wsb ----
        int base = (blk - 1888) * 1024;
#pragma unroll
        for (int it = 0; it < 4; ++it) {
            int i = base + it * 256 + t;
            Wsb[i] = f2bf(stem_w[i]);
        }
    } else if (blk < 1984) {               // ---- Wf ----
        int base = (blk - 1952) * 2048;
#pragma unroll
        for (int it = 0; it < 8; ++it) {
            int i = base + it * 256 + t;
            int o = i >> 9, k = i & 511;
            float v = 0.f;
            if (o < 4)       { if (k >= 256) v = reg_pred_w[o * 256 + (k - 256)]; }
            else if (o == 4) { if (k >= 256) v = obj_pred_w[k - 256]; }
            else if (o < 85) { if (k < 256)  v = cls_pred_w[(o - 5) * 256 + k]; }
            Wf[i] = f2bf(v);
        }
    } else {                               // ---- biases + zero page ----
        for (int i = t; i < 512; i += 256)
            bc[i] = (i < 256) ? cls_conv_b[i] : reg_conv_b[i - 256];
        if (t < 128) {
            float v = 0.f;
            if (t < 4) v = reg_pred_b[t];
            else if (t == 4) v = obj_pred_b[0];
            else if (t < 85) v = cls_pred_b[t - 5];
            bp[t] = v;
        }
        zpage[t] = 0;
    }
}

// ---------------- gemm_bt (verified) ----------------
template <int EPI>
__global__ __launch_bounds__(256, 2) void gemm_bt(
    const u16* __restrict__ A, const u16* __restrict__ B,
    const float* __restrict__ bias, void* __restrict__ Dv,
    int K, int ldd, int storeN) {
    __shared__ __align__(16) u16 lA[BM * BK];
    __shared__ __align__(16) u16 lB[BN * BK];
    const int tid = threadIdx.x;
    const int lane = tid & 63;
    const int wid = tid >> 6;
    const int wm = wid >> 1, wn = wid & 1;
    const int m0 = blockIdx.x * BM;
    const int n0 = blockIdx.y * BN;

    const int srow = lane >> 2;
    const int scol = (lane & 3) * 8;
    const int arow = lane & 15;
    const int khalf = (lane >> 4) * 8;

    f32x4 acc[4][4] = {};

    for (int k0 = 0; k0 < K; k0 += BK) {
#pragma unroll
        for (int r = 0; r < 2; ++r) {
            int row = r * 64 + wid * 16 + srow;
            gload16(A + (size_t)(m0 + row) * K + k0 + scol, lA + r * 2048 + wid * 512);
            gload16(B + (size_t)(n0 + row) * K + k0 + scol, lB + r * 2048 + wid * 512);
        }
        __syncthreads();
        s16x8 af[4], bfr[4];
#pragma unroll
        for (int f = 0; f < 4; ++f) {
            af[f]  = *(const s16x8*)&lA[(wm * 64 + f * 16 + arow) * BK + khalf];
            bfr[f] = *(const s16x8*)&lB[(wn * 64 + f * 16 + arow) * BK + khalf];
        }
#pragma unroll
        for (int i = 0; i < 4; ++i)
#pragma unroll
            for (int j = 0; j < 4; ++j)
                acc[i][j] = __builtin_amdgcn_mfma_f32_16x16x32_bf16(af[i], bfr[j],
                                                                    acc[i][j], 0, 0, 0);
        __syncthreads();
    }

#pragma unroll
    for (int i = 0; i < 4; ++i) {
        int gr0 = m0 + wm * 64 + i * 16 + (lane >> 4) * 4;
#pragma unroll
        for (int j = 0; j < 4; ++j) {
            int gc = n0 + wn * 64 + j * 16 + (lane & 15);
            if (EPI == 1 && gc >= storeN) continue;
            float bb = bias[gc];
#pragma unroll
            for (int r = 0; r < 4; ++r) {
                float v = acc[i][j][r] + bb;
                if (EPI == 0) {
                    v = v / (1.0f + __expf(-v));
                    ((u16*)Dv)[(size_t)(gr0 + r) * ldd + gc] = f2bf(v);
                } else {
                    ((float*)Dv)[(size_t)(gr0 + r) * ldd + gc] = v;
                }
            }
        }
    }
}

// ---------------- K3 fused, tri-buffer + counted vmcnt (T3+T4 derived-waits port) --------
// Geometry/layout/swizzle identical to round-4 verified kernel; ONLY the sync
// structure changes: 3 LDS buffers, stage tile t+2 during tile t, one raw
// s_barrier per tile preceded by a COUNTED vmcnt (10 = this tile's 6 stage +
// 4 rowoff issues; in-order retire guarantees tile t+1's stage landed).
__global__ __launch_bounds__(256, 2) void gemm_conv(
    const u16* __restrict__ stem, const int* __restrict__ rowoff,
    const u16* __restrict__ zpage, const u16* __restrict__ B,
    const float* __restrict__ bias, u16* __restrict__ D) {
    __shared__ __align__(16) u16 lA[3][128 * 64];
    __shared__ __align__(16) u16 lB[3][64 * 64];
    const int tid = threadIdx.x;
    const int lane = tid & 63;
    const int wid = tid >> 6;
    const int wm = wid >> 1, wn = wid & 1;
    const int m0 = blockIdx.x * 128;
    const int n0 = blockIdx.y * 64;

    const int srw = lane >> 3;
    const int cc  = lane & 7;
    const int gch = (cc ^ srw) * 8;     // inverse-swizzled source chunk (elems)
    const int arow = lane & 15;
    const int khi  = lane >> 4;
    const int sa   = arow & 7;

    f32x4 acc[4][2] = {};

    // per-thread rowoff bases (row r of the 4 A-load groups), and B base
    int rbase[4];
#pragma unroll
    for (int r = 0; r < 4; ++r) rbase[r] = (m0 + r * 32 + wid * 8 + srw) * 9;
    const u16* Bp = B + (size_t)(n0 + wid * 8 + srw) * 2304 + gch;

    int roP0[4], roP1[4];

#define ROLOAD(ROP, JV)                                                         \
    {   _Pragma("unroll")                                                       \
        for (int r = 0; r < 4; ++r) ROP[r] = rowoff[rbase[r] + (JV)]; }

#define STAGE(TS, BUF, ROP)                                                     \
    {   const int c0_ = ((TS) & 3) << 6;                                        \
        _Pragma("unroll")                                                       \
        for (int r = 0; r < 4; ++r) {                                           \
            int roff_ = ROP[r];                                                 \
            const u16* sA_ = (roff_ < 0) ? (zpage + gch)                        \
                                         : (stem + roff_ + c0_ + gch);          \
            gload16(sA_, &lA[BUF][(r * 32 + wid * 8) * 64]);                    \
        }                                                                       \
        _Pragma("unroll")                                                       \
        for (int r = 0; r < 2; ++r)                                             \
            gload16(Bp + (size_t)(r * 32) * 2304 + (TS) * 64,                   \
                    &lB[BUF][(r * 32 + wid * 8) * 64]); }

#define COMPUTE(BUF)                                                            \
    {   s16x8 af_[2][4], bf_[2][2];                                             \
        _Pragma("unroll")                                                       \
        for (int f = 0; f < 4; ++f) {                                           \
            int ra_ = (wm * 64 + f * 16 + arow) * 64;                           \
            _Pragma("unroll")                                                   \
            for (int ks = 0; ks < 2; ++ks) {                                    \
                int q_ = ks * 4 + khi;                                          \
                af_[ks][f] = *(const s16x8*)&lA[BUF][ra_ + ((q_ ^ sa) << 3)];   \
            }                                                                   \
        }                                                                       \
        _Pragma("unroll")                                                       \
        for (int jj = 0; jj < 2; ++jj) {                                        \
            int rb_ = (wn * 32 + jj * 16 + arow) * 64;                          \
            _Pragma("unroll")                                                   \
            for (int ks = 0; ks < 2; ++ks) {                                    \
                int q_ = ks * 4 + khi;                                          \
                bf_[ks][jj] = *(const s16x8*)&lB[BUF][rb_ + ((q_ ^ sa) << 3)];  \
            }                                                                   \
        }                                                                       \
        _Pragma("unroll")                                                       \
        for (int ks = 0; ks < 2; ++ks)                                          \
            _Pragma("unroll")                                                   \
            for (int i = 0; i < 4; ++i)                                         \
                _Pragma("unroll")                                               \
                for (int jj = 0; jj < 2; ++jj)                                  \
                    acc[i][jj] = __builtin_amdgcn_mfma_f32_16x16x32_bf16(       \
                        af_[ks][i], bf_[ks][jj], acc[i][jj], 0, 0, 0); }

#define TILE_END(VM)                                                            \
    {   asm volatile("s_waitcnt vmcnt(" #VM ")" ::: "memory");                  \
        __builtin_amdgcn_s_barrier(); }

    // ---- prologue: tiles 0,1 staged; roP0/roP1 hold tap j=0 (stage targets 2,3) ----
    ROLOAD(roP0, 0);
    ROLOAD(roP1, 0);
    STAGE(0, 0, roP0);
    STAGE(1, 1, roP1);
    TILE_END(6);                    // stage(0) landed

    // ---- main: 5 macro-iterations x 6 tiles (t = 6u+i, i static) ----
    for (int u = 0; u < 5; ++u) {
        const int t0 = u * 6;
        // i=0: bufC 0, bufS 2, parity 0
        STAGE(t0 + 2, 2, roP0); ROLOAD(roP0, (t0 + 4) >> 2); COMPUTE(0); TILE_END(10);
        // i=1: bufC 1, bufS 0, parity 1
        STAGE(t0 + 3, 0, roP1); ROLOAD(roP1, (t0 + 5) >> 2); COMPUTE(1); TILE_END(10);
        // i=2
        STAGE(t0 + 4, 1, roP0); ROLOAD(roP0, (t0 + 6) >> 2); COMPUTE(2); TILE_END(10);
        // i=3
        STAGE(t0 + 5, 2, roP1); ROLOAD(roP1, (t0 + 7) >> 2); COMPUTE(0); TILE_END(10);
        // i=4
        STAGE(t0 + 6, 0, roP0); ROLOAD(roP0, (t0 + 8) >> 2); COMPUTE(1); TILE_END(10);
        // i=5
        STAGE(t0 + 7, 1, roP1); ROLOAD(roP1, (t0 + 9) >> 2); COMPUTE(2); TILE_END(10);
    }
    // ---- epilogue tiles 30..35 ----
    STAGE(32, 2, roP0); ROLOAD(roP0, 34 >> 2); COMPUTE(0); TILE_END(10);  // t=30
    STAGE(33, 0, roP1); ROLOAD(roP1, 35 >> 2); COMPUTE(1); TILE_END(10);  // t=31
    STAGE(34, 1, roP0);                        COMPUTE(2); TILE_END(6);   // t=32
    STAGE(35, 2, roP1);                        COMPUTE(0); TILE_END(6);   // t=33
                                               COMPUTE(1); TILE_END(0);   // t=34
                                               COMPUTE(2);                // t=35

#undef ROLOAD
#undef STAGE
#undef COMPUTE
#undef TILE_END

#pragma unroll
    for (int i = 0; i < 4; ++i) {
        int gr0 = m0 + wm * 64 + i * 16 + khi * 4;
#pragma unroll
        for (int jj = 0; jj < 2; ++jj) {
            int gc = n0 + wn * 32 + jj * 16 + arow;
            float bb = bias[gc];
#pragma unroll
            for (int r = 0; r < 4; ++r) {
                float v = acc[i][jj][r] + bb;
                v = v / (1.0f + __expf(-v));
                D[(size_t)(gr0 + r) * 512 + gc] = f2bf(v);
            }
        }
    }
}

// ---------------- K4: out[m, p<85] = feat[m,:] @ Wf^T + bp ----------------
__global__ __launch_bounds__(256, 4) void gemm_pred(
    const u16* __restrict__ A, const u16* __restrict__ B,
    const float* __restrict__ bias, float* __restrict__ D) {
    __shared__ __align__(16) u16 lA[64 * 64];
    __shared__ __align__(16) u16 lB[64 * 64];
    const int tid = threadIdx.x;
    const int lane = tid & 63;
    const int wid = tid >> 6;
    const int wm = wid >> 1, wn = wid & 1;
    const int m0 = blockIdx.x * 64;
    const int n0 = blockIdx.y * 64;

    const int srw = lane >> 3;
    const int cc  = lane & 7;
    const int arow = lane & 15;
    const int khi  = lane >> 4;

    f32x4 acc[2][2] = {};

    for (int k0 = 0; k0 < 512; k0 += 64) {
        const int gch = (cc ^ srw) * 8;
#pragma unroll
        for (int r = 0; r < 2; ++r) {
            int row = r * 32 + wid * 8 + srw;
            gload16(A + (size_t)(m0 + row) * 512 + k0 + gch,
                    lA + (r * 32 + wid * 8) * 64);
            gload16(B + (size_t)(n0 + row) * 512 + k0 + gch,
                    lB + (r * 32 + wid * 8) * 64);
        }
        __syncthreads();
        s16x8 af[2][2], bfr[2][2];
        const int sa = arow & 7;
#pragma unroll
        for (int f = 0; f < 2; ++f) {
            int ra = (wm * 32 + f * 16 + arow) * 64;
            int rb = (wn * 32 + f * 16 + arow) * 64;
#pragma unroll
            for (int ks = 0; ks < 2; ++ks) {
                int q = ks * 4 + khi;
                af[ks][f]  = *(const s16x8*)&lA[ra + ((q ^ sa) << 3)];
                bfr[ks][f] = *(const s16x8*)&lB[rb + ((q ^ sa) << 3)];
            }
        }
#pragma unroll
        for (int ks = 0; ks < 2; ++ks)
#pragma unroll
            for (int i = 0; i < 2; ++i)
#pragma unroll
                for (int jj = 0; jj < 2; ++jj)
                    acc[i][jj] = __builtin_amdgcn_mfma_f32_16x16x32_bf16(
                        af[ks][i], bfr[ks][jj], acc[i][jj], 0, 0, 0);
        __syncthreads();
    }

#pragma unroll
    for (int i = 0; i < 2; ++i) {
        int gr0 = m0 + wm * 32 + i * 16 + khi * 4;
#pragma unroll
        for (int jj = 0; jj < 2; ++jj) {
            int gc = n0 + wn * 32 + jj * 16 + arow;
            if (gc >= 85) continue;
            float bb = bias[gc];
#pragma unroll
            for (int r = 0; r < 4; ++r)
                D[(size_t)(gr0 + r) * 85 + gc] = acc[i][jj][r] + bb;
        }
    }
}

extern "C" void kernel_launch(void* const* d_in, const int* in_sizes, int n_in,
                              void* d_out, int out_size, void* d_ws, size_t ws_size,
                              hipStream_t stream) {
    const float* x          = (const float*)d_in[0];
    const int*   idx        = (const int*)d_in[1];
    const float* stem_w     = (const float*)d_in[2];
    const float* stem_b     = (const float*)d_in[3];
    const float* cls_conv_w = (const float*)d_in[4];
    const float* cls_conv_b = (const float*)d_in[5];
    const float* reg_conv_w = (const float*)d_in[6];
    const float* reg_conv_b = (const float*)d_in[7];
    const float* cls_pred_w = (const float*)d_in[8];
    const float* cls_pred_b = (const float*)d_in[9];
    const float* reg_pred_w = (const float*)d_in[10];
    const float* reg_pred_b = (const float*)d_in[11];
    const float* obj_pred_w = (const float*)d_in[12];
    const float* obj_pred_b = (const float*)d_in[13];
    float* out = (float*)d_out;
    char* ws = (char*)d_ws;

    u16*  xT     = (u16*)(ws);                    // 26,214,400
    u16*  stem   = (u16*)(ws + 26214400);         // 26,214,400 (NHWC bf16)
    u16*  feat   = (u16*)(ws + 52428800);         // 16,777,216
    u16*  Wc     = (u16*)(ws + 69206016);         // 2,359,296
    u16*  Wf     = (u16*)(ws + 71565312);         // 131,072
    u16*  Wsb    = (u16*)(ws + 71696384);         // 131,072
    int*  rowoff = (int*)(ws + 71827456);         // 589,824
    u16*  zpage  = (u16*)(ws + 72417280);         // 512 B
    float* bc    = (float*)(ws + 72417792);       // 2048
    float* bp    = (float*)(ws + 72419840);       // 512

    fused_pre<<<1985, 256, 0, stream>>>(x, idx, stem_w,
                                        cls_conv_w, cls_conv_b, reg_conv_w, reg_conv_b,
                                        cls_pred_w, cls_pred_b, reg_pred_w, reg_pred_b,
                                        obj_pred_w, obj_pred_b,
                                        xT, Wsb, Wc, Wf, rowoff, bc, bp, zpage);
    gemm_bt<0><<<dim3(400, 2), 256, 0, stream>>>(xT, Wsb, stem_b, stem, 256, 256, 256);
    gemm_conv<<<dim3(128, 8), 256, 0, stream>>>(stem, rowoff, zpage, Wc, bc, feat);
    gemm_pred<<<dim3(256, 2), 256, 0, stream>>>(feat, Wf, bp, out);
}

// Round 9
// 93.604 us; speedup vs baseline: 1.1525x; 1.1525x over previous
//
#include <hip/hip_runtime.h>

typedef unsigned short u16;
typedef __attribute__((ext_vector_type(4))) float f32x4;
typedef __attribute__((ext_vector_type(8))) short s16x8;

#define BM 128
#define BN 128
#define BK 32

__device__ inline float bf2f(u16 u) {
    unsigned v = ((unsigned)u) << 16;
    return __builtin_bit_cast(float, v);
}
__device__ inline u16 f2bf(float f) {
    unsigned u = __builtin_bit_cast(unsigned, f);
    unsigned r = (u + 0x7FFFu + ((u >> 16) & 1u)) >> 16;
    return (u16)r;
}

typedef const __attribute__((address_space(1))) void* gptr_t;
typedef __attribute__((address_space(3))) void* lptr_t;
__device__ inline void gload16(const u16* gp, u16* lp) {
    __builtin_amdgcn_global_load_lds((gptr_t)gp, (lptr_t)lp, 16, 0, 0);
}

// ---------------- fused_pre: transpose + weight permutes + rowoff + biases ----------------
__global__ __launch_bounds__(256) void fused_pre(
    const float* __restrict__ x, const int* __restrict__ idx,
    const float* __restrict__ stem_w,
    const float* __restrict__ cls_conv_w, const float* __restrict__ cls_conv_b,
    const float* __restrict__ reg_conv_w, const float* __restrict__ reg_conv_b,
    const float* __restrict__ cls_pred_w, const float* __restrict__ cls_pred_b,
    const float* __restrict__ reg_pred_w, const float* __restrict__ reg_pred_b,
    const float* __restrict__ obj_pred_w, const float* __restrict__ obj_pred_b,
    u16* __restrict__ xT, u16* __restrict__ Wsb, u16* __restrict__ Wc,
    u16* __restrict__ Wf, int* __restrict__ rowoff,
    float* __restrict__ bc, float* __restrict__ bp, u16* __restrict__ zpage) {
    __shared__ u16 tile[64 * 258];
    const int blk = blockIdx.x;
    const int t = threadIdx.x;

    if (blk < 800) {                       // ---- transpose ----
        int b = blk / 100, hw0 = (blk % 100) * 64;
        int l = t & 63, w = t >> 6;
        const float* xb = x + (size_t)b * 256 * 6400 + hw0 + l;
#pragma unroll 4
        for (int k = 0; k < 64; ++k) {
            int c = w + k * 4;
            tile[l * 258 + c] = f2bf(xb[(size_t)c * 6400]);
        }
        __syncthreads();
        u16* outb = xT + ((size_t)b * 6400 + hw0) * 256;
#pragma unroll
        for (int i = 0; i < 8; ++i) {
            int hw = w * 16 + i * 2 + (l >> 5);
            int c = (l & 31) * 8;
            *(int4*)(outb + (size_t)hw * 256 + c) = *(const int4*)&tile[hw * 258 + c];
        }
    } else if (blk < 1312) {               // ---- Wc permute ----
        int o = blk - 800;
        const float* src = (o < 256) ? (cls_conv_w + (size_t)o * 2304)
                                     : (reg_conv_w + (size_t)(o - 256) * 2304);
        u16* dst = Wc + (size_t)o * 2304;
#pragma unroll
        for (int it = 0; it < 9; ++it) {
            int kk = it * 256 + t;
            int j = kk >> 8, c = kk & 255;
            dst[kk] = f2bf(src[c * 9 + j]);
        }
    } else if (blk < 1888) {               // ---- rowoff ----
        int i = (blk - 1312) * 256 + t;
        int n = i / 9, j = i % 9;
        int b = idx[n * 3 + 0], y = idx[n * 3 + 1], xx0 = idx[n * 3 + 2];
        int yy = y + j / 3 - 1;
        int xx = xx0 + j % 3 - 1;
        rowoff[i] = ((unsigned)yy < 80u && (unsigned)xx < 80u)
                        ? (b * 6400 + yy * 80 + xx) * 256 : -1;
    } else if (blk < 1952) {               // ---- Wsb ----
        int base = (blk - 1888) * 1024;
#pragma unroll
        for (int it = 0; it < 4; ++it) {
            int i = base + it * 256 + t;
            Wsb[i] = f2bf(stem_w[i]);
        }
    } else if (blk < 1984) {               // ---- Wf ----
        int base = (blk - 1952) * 2048;
#pragma unroll
        for (int it = 0; it < 8; ++it) {
            int i = base + it * 256 + t;
            int o = i >> 9, k = i & 511;
            float v = 0.f;
            if (o < 4)       { if (k >= 256) v = reg_pred_w[o * 256 + (k - 256)]; }
            else if (o == 4) { if (k >= 256) v = obj_pred_w[k - 256]; }
            else if (o < 85) { if (k < 256)  v = cls_pred_w[(o - 5) * 256 + k]; }
            Wf[i] = f2bf(v);
        }
    } else {                               // ---- biases + zero page ----
        for (int i = t; i < 512; i += 256)
            bc[i] = (i < 256) ? cls_conv_b[i] : reg_conv_b[i - 256];
        if (t < 128) {
            float v = 0.f;
            if (t < 4) v = reg_pred_b[t];
            else if (t == 4) v = obj_pred_b[0];
            else if (t < 85) v = cls_pred_b[t - 5];
            bp[t] = v;
        }
        zpage[t] = 0;
    }
}

// ---------------- gemm_bt (verified) ----------------
template <int EPI>
__global__ __launch_bounds__(256, 2) void gemm_bt(
    const u16* __restrict__ A, const u16* __restrict__ B,
    const float* __restrict__ bias, void* __restrict__ Dv,
    int K, int ldd, int storeN) {
    __shared__ __align__(16) u16 lA[BM * BK];
    __shared__ __align__(16) u16 lB[BN * BK];
    const int tid = threadIdx.x;
    const int lane = tid & 63;
    const int wid = tid >> 6;
    const int wm = wid >> 1, wn = wid & 1;
    const int m0 = blockIdx.x * BM;
    const int n0 = blockIdx.y * BN;

    const int srow = lane >> 2;
    const int scol = (lane & 3) * 8;
    const int arow = lane & 15;
    const int khalf = (lane >> 4) * 8;

    f32x4 acc[4][4] = {};

    for (int k0 = 0; k0 < K; k0 += BK) {
#pragma unroll
        for (int r = 0; r < 2; ++r) {
            int row = r * 64 + wid * 16 + srow;
            gload16(A + (size_t)(m0 + row) * K + k0 + scol, lA + r * 2048 + wid * 512);
            gload16(B + (size_t)(n0 + row) * K + k0 + scol, lB + r * 2048 + wid * 512);
        }
        __syncthreads();
        s16x8 af[4], bfr[4];
#pragma unroll
        for (int f = 0; f < 4; ++f) {
            af[f]  = *(const s16x8*)&lA[(wm * 64 + f * 16 + arow) * BK + khalf];
            bfr[f] = *(const s16x8*)&lB[(wn * 64 + f * 16 + arow) * BK + khalf];
        }
#pragma unroll
        for (int i = 0; i < 4; ++i)
#pragma unroll
            for (int j = 0; j < 4; ++j)
                acc[i][j] = __builtin_amdgcn_mfma_f32_16x16x32_bf16(af[i], bfr[j],
                                                                    acc[i][j], 0, 0, 0);
        __syncthreads();
    }

#pragma unroll
    for (int i = 0; i < 4; ++i) {
        int gr0 = m0 + wm * 64 + i * 16 + (lane >> 4) * 4;
#pragma unroll
        for (int j = 0; j < 4; ++j) {
            int gc = n0 + wn * 64 + j * 16 + (lane & 15);
            if (EPI == 1 && gc >= storeN) continue;
            float bb = bias[gc];
#pragma unroll
            for (int r = 0; r < 4; ++r) {
                float v = acc[i][j][r] + bb;
                if (EPI == 0) {
                    v = v / (1.0f + __expf(-v));
                    ((u16*)Dv)[(size_t)(gr0 + r) * ldd + gc] = f2bf(v);
                } else {
                    ((float*)Dv)[(size_t)(gr0 + r) * ldd + gc] = v;
                }
            }
        }
    }
}

// ---------------- K3 fused (r4 structure + hoisted rowoff): 2-phase, 4 blocks/CU --------
// feat = silu( gather(stem)[m,:] @ Wc^T + bc ).  BM=128, BN=64, BK=64.
// All 36 rowoff values (4 row-groups x 9 taps) loaded to registers in the
// prologue (fully-unrolled tap loop -> static indices), so each K-step's
// stage has NO dependent-load chain: B first (independent), then A from regs.
__global__ __launch_bounds__(256, 4) void gemm_conv(
    const u16* __restrict__ stem, const int* __restrict__ rowoff,
    const u16* __restrict__ zpage, const u16* __restrict__ B,
    const float* __restrict__ bias, u16* __restrict__ D) {
    __shared__ __align__(16) u16 lA[128 * 64];
    __shared__ __align__(16) u16 lB[64 * 64];
    const int tid = threadIdx.x;
    const int lane = tid & 63;
    const int wid = tid >> 6;
    const int wm = wid >> 1, wn = wid & 1;
    const int m0 = blockIdx.x * 128;
    const int n0 = blockIdx.y * 64;

    const int srw = lane >> 3;          // staging row within 8-row group (= row&7)
    const int cc  = lane & 7;           // staging chunk slot (16B units)
    const int gch = (cc ^ srw) * 8;     // inverse-swizzled source chunk
    const int arow = lane & 15;
    const int khi  = lane >> 4;         // 0..3
    const int sa   = arow & 7;

    // hoisted rowoff (static indices only)
    int ro[4][9];
#pragma unroll
    for (int r = 0; r < 4; ++r) {
        const int rb = (m0 + r * 32 + wid * 8 + srw) * 9;
#pragma unroll
        for (int j = 0; j < 9; ++j) ro[r][j] = rowoff[rb + j];
    }
    const u16* Bp = B + (size_t)(n0 + wid * 8 + srw) * 2304 + gch;

    f32x4 acc[4][2] = {};

#pragma unroll
    for (int j = 0; j < 9; ++j) {
#pragma unroll
        for (int q4 = 0; q4 < 4; ++q4) {
            const int c0 = q4 << 6;             // channel base within tap
            const int k0 = j * 256 + c0;
            // B stage first (no deps), then A (addresses already in registers)
#pragma unroll
            for (int r = 0; r < 2; ++r)
                gload16(Bp + (size_t)(r * 32) * 2304 + k0,
                        lB + (r * 32 + wid * 8) * 64);
#pragma unroll
            for (int r = 0; r < 4; ++r) {
                int roff = ro[r][j];
                const u16* srcA = (roff < 0) ? (zpage + gch)
                                             : (stem + roff + c0 + gch);
                gload16(srcA, lA + (r * 32 + wid * 8) * 64);
            }
            __syncthreads();
            s16x8 af[2][4], bfr[2][2];
#pragma unroll
            for (int f = 0; f < 4; ++f) {
                int ra = (wm * 64 + f * 16 + arow) * 64;
#pragma unroll
                for (int ks = 0; ks < 2; ++ks) {
                    int q = ks * 4 + khi;
                    af[ks][f] = *(const s16x8*)&lA[ra + ((q ^ sa) << 3)];
                }
            }
#pragma unroll
            for (int jj = 0; jj < 2; ++jj) {
                int rb2 = (wn * 32 + jj * 16 + arow) * 64;
#pragma unroll
                for (int ks = 0; ks < 2; ++ks) {
                    int q = ks * 4 + khi;
                    bfr[ks][jj] = *(const s16x8*)&lB[rb2 + ((q ^ sa) << 3)];
                }
            }
#pragma unroll
            for (int ks = 0; ks < 2; ++ks)
#pragma unroll
                for (int i = 0; i < 4; ++i)
#pragma unroll
                    for (int jj = 0; jj < 2; ++jj)
                        acc[i][jj] = __builtin_amdgcn_mfma_f32_16x16x32_bf16(
                            af[ks][i], bfr[ks][jj], acc[i][jj], 0, 0, 0);
            __syncthreads();
        }
    }

#pragma unroll
    for (int i = 0; i < 4; ++i) {
        int gr0 = m0 + wm * 64 + i * 16 + khi * 4;
#pragma unroll
        for (int jj = 0; jj < 2; ++jj) {
            int gc = n0 + wn * 32 + jj * 16 + arow;
            float bb = bias[gc];
#pragma unroll
            for (int r = 0; r < 4; ++r) {
                float v = acc[i][jj][r] + bb;
                v = v / (1.0f + __expf(-v));
                D[(size_t)(gr0 + r) * 512 + gc] = f2bf(v);
            }
        }
    }
}

// ---------------- K4: out[m, p<85] = feat[m,:] @ Wf^T + bp ----------------
__global__ __launch_bounds__(256, 4) void gemm_pred(
    const u16* __restrict__ A, const u16* __restrict__ B,
    const float* __restrict__ bias, float* __restrict__ D) {
    __shared__ __align__(16) u16 lA[64 * 64];
    __shared__ __align__(16) u16 lB[64 * 64];
    const int tid = threadIdx.x;
    const int lane = tid & 63;
    const int wid = tid >> 6;
    const int wm = wid >> 1, wn = wid & 1;
    const int m0 = blockIdx.x * 64;
    const int n0 = blockIdx.y * 64;

    const int srw = lane >> 3;
    const int cc  = lane & 7;
    const int arow = lane & 15;
    const int khi  = lane >> 4;

    f32x4 acc[2][2] = {};

    for (int k0 = 0; k0 < 512; k0 += 64) {
        const int gch = (cc ^ srw) * 8;
#pragma unroll
        for (int r = 0; r < 2; ++r) {
            int row = r * 32 + wid * 8 + srw;
            gload16(A + (size_t)(m0 + row) * 512 + k0 + gch,
                    lA + (r * 32 + wid * 8) * 64);
            gload16(B + (size_t)(n0 + row) * 512 + k0 + gch,
                    lB + (r * 32 + wid * 8) * 64);
        }
        __syncthreads();
        s16x8 af[2][2], bfr[2][2];
        const int sa = arow & 7;
#pragma unroll
        for (int f = 0; f < 2; ++f) {
            int ra = (wm * 32 + f * 16 + arow) * 64;
            int rb = (wn * 32 + f * 16 + arow) * 64;
#pragma unroll
            for (int ks = 0; ks < 2; ++ks) {
                int q = ks * 4 + khi;
                af[ks][f]  = *(const s16x8*)&lA[ra + ((q ^ sa) << 3)];
                bfr[ks][f] = *(const s16x8*)&lB[rb + ((q ^ sa) << 3)];
            }
        }
#pragma unroll
        for (int ks = 0; ks < 2; ++ks)
#pragma unroll
            for (int i = 0; i < 2; ++i)
#pragma unroll
                for (int jj = 0; jj < 2; ++jj)
                    acc[i][jj] = __builtin_amdgcn_mfma_f32_16x16x32_bf16(
                        af[ks][i], bfr[ks][jj], acc[i][jj], 0, 0, 0);
        __syncthreads();
    }

#pragma unroll
    for (int i = 0; i < 2; ++i) {
        int gr0 = m0 + wm * 32 + i * 16 + khi * 4;
#pragma unroll
        for (int jj = 0; jj < 2; ++jj) {
            int gc = n0 + wn * 32 + jj * 16 + arow;
            if (gc >= 85) continue;
            float bb = bias[gc];
#pragma unroll
            for (int r = 0; r < 4; ++r)
                D[(size_t)(gr0 + r) * 85 + gc] = acc[i][jj][r] + bb;
        }
    }
}

extern "C" void kernel_launch(void* const* d_in, const int* in_sizes, int n_in,
                              void* d_out, int out_size, void* d_ws, size_t ws_size,
                              hipStream_t stream) {
    const float* x          = (const float*)d_in[0];
    const int*   idx        = (const int*)d_in[1];
    const float* stem_w     = (const float*)d_in[2];
    const float* stem_b     = (const float*)d_in[3];
    const float* cls_conv_w = (const float*)d_in[4];
    const float* cls_conv_b = (const float*)d_in[5];
    const float* reg_conv_w = (const float*)d_in[6];
    const float* reg_conv_b = (const float*)d_in[7];
    const float* cls_pred_w = (const float*)d_in[8];
    const float* cls_pred_b = (const float*)d_in[9];
    const float* reg_pred_w = (const float*)d_in[10];
    const float* reg_pred_b = (const float*)d_in[11];
    const float* obj_pred_w = (const float*)d_in[12];
    const float* obj_pred_b = (const float*)d_in[13];
    float* out = (float*)d_out;
    char* ws = (char*)d_ws;

    u16*  xT     = (u16*)(ws);                    // 26,214,400
    u16*  stem   = (u16*)(ws + 26214400);         // 26,214,400 (NHWC bf16)
    u16*  feat   = (u16*)(ws + 52428800);         // 16,777,216
    u16*  Wc     = (u16*)(ws + 69206016);         // 2,359,296
    u16*  Wf     = (u16*)(ws + 71565312);         // 131,072
    u16*  Wsb    = (u16*)(ws + 71696384);         // 131,072
    int*  rowoff = (int*)(ws + 71827456);         // 589,824
    u16*  zpage  = (u16*)(ws + 72417280);         // 512 B
    float* bc    = (float*)(ws + 72417792);       // 2048
    float* bp    = (float*)(ws + 72419840);       // 512

    fused_pre<<<1985, 256, 0, stream>>>(x, idx, stem_w,
                                        cls_conv_w, cls_conv_b, reg_conv_w, reg_conv_b,
                                        cls_pred_w, cls_pred_b, reg_pred_w, reg_pred_b,
                                        obj_pred_w, obj_pred_b,
                                        xT, Wsb, Wc, Wf, rowoff, bc, bp, zpage);
    gemm_bt<0><<<dim3(400, 2), 256, 0, stream>>>(xT, Wsb, stem_b, stem, 256, 256, 256);
    gemm_conv<<<dim3(128, 8), 256, 0, stream>>>(stem, rowoff, zpage, Wc, bc, feat);
    gemm_pred<<<dim3(256, 2), 256, 0, stream>>>(feat, Wf, bp, out);
}

// Round 10
// 92.923 us; speedup vs baseline: 1.1609x; 1.0073x over previous
//
#include <hip/hip_runtime.h>

typedef unsigned short u16;
typedef __attribute__((ext_vector_type(4))) float f32x4;
typedef __attribute__((ext_vector_type(8))) short s16x8;

#define BM 128
#define BN 128
#define BK 32

__device__ inline float bf2f(u16 u) {
    unsigned v = ((unsigned)u) << 16;
    return __builtin_bit_cast(float, v);
}
__device__ inline u16 f2bf(float f) {
    unsigned u = __builtin_bit_cast(unsigned, f);
    unsigned r = (u + 0x7FFFu + ((u >> 16) & 1u)) >> 16;
    return (u16)r;
}

typedef const __attribute__((address_space(1))) void* gptr_t;
typedef __attribute__((address_space(3))) void* lptr_t;
__device__ inline void gload16(const u16* gp, u16* lp) {
    __builtin_amdgcn_global_load_lds((gptr_t)gp, (lptr_t)lp, 16, 0, 0);
}

// ---------------- fused_pre: weight permutes + rowoff + biases (transpose removed) -------
//   [0,512)     : Wc row o = blk   (k' = j*256+c permute)
//   [512,1088)  : rowoff (16384*9)
//   [1088,1152) : Wsb (stem_w -> bf16)
//   [1152,1184) : Wf (fused pred weight, zero-padded)
//   1184        : bc, bp, zpage
__global__ __launch_bounds__(256) void fused_pre(
    const int* __restrict__ idx,
    const float* __restrict__ stem_w,
    const float* __restrict__ cls_conv_w, const float* __restrict__ cls_conv_b,
    const float* __restrict__ reg_conv_w, const float* __restrict__ reg_conv_b,
    const float* __restrict__ cls_pred_w, const float* __restrict__ cls_pred_b,
    const float* __restrict__ reg_pred_w, const float* __restrict__ reg_pred_b,
    const float* __restrict__ obj_pred_w, const float* __restrict__ obj_pred_b,
    u16* __restrict__ Wsb, u16* __restrict__ Wc,
    u16* __restrict__ Wf, int* __restrict__ rowoff,
    float* __restrict__ bc, float* __restrict__ bp, u16* __restrict__ zpage) {
    const int blk = blockIdx.x;
    const int t = threadIdx.x;

    if (blk < 512) {                       // ---- Wc permute ----
        int o = blk;
        const float* src = (o < 256) ? (cls_conv_w + (size_t)o * 2304)
                                     : (reg_conv_w + (size_t)(o - 256) * 2304);
        u16* dst = Wc + (size_t)o * 2304;
#pragma unroll
        for (int it = 0; it < 9; ++it) {
            int kk = it * 256 + t;
            int j = kk >> 8, c = kk & 255;
            dst[kk] = f2bf(src[c * 9 + j]);
        }
    } else if (blk < 1088) {               // ---- rowoff ----
        int i = (blk - 512) * 256 + t;
        int n = i / 9, j = i % 9;
        int b = idx[n * 3 + 0], y = idx[n * 3 + 1], xx0 = idx[n * 3 + 2];
        int yy = y + j / 3 - 1;
        int xx = xx0 + j % 3 - 1;
        rowoff[i] = ((unsigned)yy < 80u && (unsigned)xx < 80u)
                        ? (b * 6400 + yy * 80 + xx) * 256 : -1;
    } else if (blk < 1152) {               // ---- Wsb ----
        int base = (blk - 1088) * 1024;
#pragma unroll
        for (int it = 0; it < 4; ++it) {
            int i = base + it * 256 + t;
            Wsb[i] = f2bf(stem_w[i]);
        }
    } else if (blk < 1184) {               // ---- Wf ----
        int base = (blk - 1152) * 2048;
#pragma unroll
        for (int it = 0; it < 8; ++it) {
            int i = base + it * 256 + t;
            int o = i >> 9, k = i & 511;
            float v = 0.f;
            if (o < 4)       { if (k >= 256) v = reg_pred_w[o * 256 + (k - 256)]; }
            else if (o == 4) { if (k >= 256) v = obj_pred_w[k - 256]; }
            else if (o < 85) { if (k < 256)  v = cls_pred_w[(o - 5) * 256 + k]; }
            Wf[i] = f2bf(v);
        }
    } else {                               // ---- biases + zero page ----
        for (int i = t; i < 512; i += 256)
            bc[i] = (i < 256) ? cls_conv_b[i] : reg_conv_b[i - 256];
        if (t < 128) {
            float v = 0.f;
            if (t < 4) v = reg_pred_b[t];
            else if (t == 4) v = obj_pred_b[0];
            else if (t < 85) v = cls_pred_b[t - 5];
            bp[t] = v;
        }
        zpage[t] = 0;
    }
}

// ---------------- gemm_stem: stem = silu(x^T @ Wsb^T + b), transpose fused ----------------
// A-tile [128 hw][64 c] staged by coalesced f32 loads (lanes span hw) + in-reg
// bf16 pack + ds_write_b128 into stride-72-padded LDS (conflict-free, no XOR).
// B-tile via verified gload16 + XOR path.  BM=128, BN=64, BK=64; grid (400,4).
__global__ __launch_bounds__(256, 4) void gemm_stem(
    const float* __restrict__ x, const u16* __restrict__ Wsb,
    const float* __restrict__ bias, u16* __restrict__ stem) {
    __shared__ __align__(16) u16 lA[128 * 72];
    __shared__ __align__(16) u16 lB[64 * 64];
    const int tid = threadIdx.x;
    const int lane = tid & 63;
    const int wid = tid >> 6;
    const int wm = wid >> 1, wn = wid & 1;
    const int bx = blockIdx.x;             // 0..399 ; 50 blocks per image
    const int b   = bx / 50;
    const int hwb = (bx % 50) * 128;
    const int n0 = blockIdx.y * 64;

    const int srw = lane >> 3;
    const int cc  = lane & 7;
    const int gch = (cc ^ srw) * 8;
    const int arow = lane & 15;
    const int khi  = lane >> 4;
    const int sa   = arow & 7;

    const float* xb = x + (size_t)b * 256 * 6400 + hwb;
    const u16* Bp = Wsb + (size_t)(n0 + wid * 8 + srw) * 256 + gch;

    f32x4 acc[4][2] = {};

    for (int k0 = 0; k0 < 256; k0 += 64) {
        // B stage (async, vmcnt)
#pragma unroll
        for (int r = 0; r < 2; ++r)
            gload16(Bp + (size_t)(r * 32) * 256 + k0,
                    lB + (r * 32 + wid * 8) * 64);
        // A stage: fused transpose+cast (lgkmcnt)
#pragma unroll
        for (int u = 0; u < 4; ++u) {
            const int hw  = (u & 1) * 64 + lane;
            const int oct = (u >> 1) * 4 + wid;
            union { u16 s[8]; s16x8 v; } pk;
#pragma unroll
            for (int jj = 0; jj < 8; ++jj)
                pk.s[jj] = f2bf(xb[(size_t)(k0 + oct * 8 + jj) * 6400 + hw]);
            *(s16x8*)&lA[hw * 72 + oct * 8] = pk.v;
        }
        __syncthreads();
        s16x8 af[2][4], bfr[2][2];
#pragma unroll
        for (int f = 0; f < 4; ++f) {
            int ra = (wm * 64 + f * 16 + arow) * 72;
#pragma unroll
            for (int ks = 0; ks < 2; ++ks)
                af[ks][f] = *(const s16x8*)&lA[ra + (ks * 4 + khi) * 8];
        }
#pragma unroll
        for (int jj = 0; jj < 2; ++jj) {
            int rb2 = (wn * 32 + jj * 16 + arow) * 64;
#pragma unroll
            for (int ks = 0; ks < 2; ++ks) {
                int q = ks * 4 + khi;
                bfr[ks][jj] = *(const s16x8*)&lB[rb2 + ((q ^ sa) << 3)];
            }
        }
#pragma unroll
        for (int ks = 0; ks < 2; ++ks)
#pragma unroll
            for (int i = 0; i < 4; ++i)
#pragma unroll
                for (int jj = 0; jj < 2; ++jj)
                    acc[i][jj] = __builtin_amdgcn_mfma_f32_16x16x32_bf16(
                        af[ks][i], bfr[ks][jj], acc[i][jj], 0, 0, 0);
        __syncthreads();
    }

#pragma unroll
    for (int i = 0; i < 4; ++i) {
        int lr0 = wm * 64 + i * 16 + khi * 4;
#pragma unroll
        for (int jj = 0; jj < 2; ++jj) {
            int gc = n0 + wn * 32 + jj * 16 + arow;
            float bb = bias[gc];
#pragma unroll
            for (int r = 0; r < 4; ++r) {
                float v = acc[i][jj][r] + bb;
                v = v / (1.0f + __expf(-v));
                stem[(size_t)(b * 6400 + hwb + lr0 + r) * 256 + gc] = f2bf(v);
            }
        }
    }
}

// ---------------- K3 fused (r9 verified): 2-phase, hoisted rowoff, 4 blocks/CU ----------
__global__ __launch_bounds__(256, 4) void gemm_conv(
    const u16* __restrict__ stem, const int* __restrict__ rowoff,
    const u16* __restrict__ zpage, const u16* __restrict__ B,
    const float* __restrict__ bias, u16* __restrict__ D) {
    __shared__ __align__(16) u16 lA[128 * 64];
    __shared__ __align__(16) u16 lB[64 * 64];
    const int tid = threadIdx.x;
    const int lane = tid & 63;
    const int wid = tid >> 6;
    const int wm = wid >> 1, wn = wid & 1;
    const int m0 = blockIdx.x * 128;
    const int n0 = blockIdx.y * 64;

    const int srw = lane >> 3;
    const int cc  = lane & 7;
    const int gch = (cc ^ srw) * 8;
    const int arow = lane & 15;
    const int khi  = lane >> 4;
    const int sa   = arow & 7;

    int ro[4][9];
#pragma unroll
    for (int r = 0; r < 4; ++r) {
        const int rb = (m0 + r * 32 + wid * 8 + srw) * 9;
#pragma unroll
        for (int j = 0; j < 9; ++j) ro[r][j] = rowoff[rb + j];
    }
    const u16* Bp = B + (size_t)(n0 + wid * 8 + srw) * 2304 + gch;

    f32x4 acc[4][2] = {};

#pragma unroll
    for (int j = 0; j < 9; ++j) {
#pragma unroll
        for (int q4 = 0; q4 < 4; ++q4) {
            const int c0 = q4 << 6;
            const int k0 = j * 256 + c0;
#pragma unroll
            for (int r = 0; r < 2; ++r)
                gload16(Bp + (size_t)(r * 32) * 2304 + k0,
                        lB + (r * 32 + wid * 8) * 64);
#pragma unroll
            for (int r = 0; r < 4; ++r) {
                int roff = ro[r][j];
                const u16* srcA = (roff < 0) ? (zpage + gch)
                                             : (stem + roff + c0 + gch);
                gload16(srcA, lA + (r * 32 + wid * 8) * 64);
            }
            __syncthreads();
            s16x8 af[2][4], bfr[2][2];
#pragma unroll
            for (int f = 0; f < 4; ++f) {
                int ra = (wm * 64 + f * 16 + arow) * 64;
#pragma unroll
                for (int ks = 0; ks < 2; ++ks) {
                    int q = ks * 4 + khi;
                    af[ks][f] = *(const s16x8*)&lA[ra + ((q ^ sa) << 3)];
                }
            }
#pragma unroll
            for (int jj = 0; jj < 2; ++jj) {
                int rb2 = (wn * 32 + jj * 16 + arow) * 64;
#pragma unroll
                for (int ks = 0; ks < 2; ++ks) {
                    int q = ks * 4 + khi;
                    bfr[ks][jj] = *(const s16x8*)&lB[rb2 + ((q ^ sa) << 3)];
                }
            }
#pragma unroll
            for (int ks = 0; ks < 2; ++ks)
#pragma unroll
                for (int i = 0; i < 4; ++i)
#pragma unroll
                    for (int jj = 0; jj < 2; ++jj)
                        acc[i][jj] = __builtin_amdgcn_mfma_f32_16x16x32_bf16(
                            af[ks][i], bfr[ks][jj], acc[i][jj], 0, 0, 0);
            __syncthreads();
        }
    }

#pragma unroll
    for (int i = 0; i < 4; ++i) {
        int gr0 = m0 + wm * 64 + i * 16 + khi * 4;
#pragma unroll
        for (int jj = 0; jj < 2; ++jj) {
            int gc = n0 + wn * 32 + jj * 16 + arow;
            float bb = bias[gc];
#pragma unroll
            for (int r = 0; r < 4; ++r) {
                float v = acc[i][jj][r] + bb;
                v = v / (1.0f + __expf(-v));
                D[(size_t)(gr0 + r) * 512 + gc] = f2bf(v);
            }
        }
    }
}

// ---------------- K4: out[m, p<85] = feat[m,:] @ Wf^T + bp ----------------
__global__ __launch_bounds__(256, 4) void gemm_pred(
    const u16* __restrict__ A, const u16* __restrict__ B,
    const float* __restrict__ bias, float* __restrict__ D) {
    __shared__ __align__(16) u16 lA[64 * 64];
    __shared__ __align__(16) u16 lB[64 * 64];
    const int tid = threadIdx.x;
    const int lane = tid & 63;
    const int wid = tid >> 6;
    const int wm = wid >> 1, wn = wid & 1;
    const int m0 = blockIdx.x * 64;
    const int n0 = blockIdx.y * 64;

    const int srw = lane >> 3;
    const int cc  = lane & 7;
    const int arow = lane & 15;
    const int khi  = lane >> 4;

    f32x4 acc[2][2] = {};

    for (int k0 = 0; k0 < 512; k0 += 64) {
        const int gch = (cc ^ srw) * 8;
#pragma unroll
        for (int r = 0; r < 2; ++r) {
            int row = r * 32 + wid * 8 + srw;
            gload16(A + (size_t)(m0 + row) * 512 + k0 + gch,
                    lA + (r * 32 + wid * 8) * 64);
            gload16(B + (size_t)(n0 + row) * 512 + k0 + gch,
                    lB + (r * 32 + wid * 8) * 64);
        }
        __syncthreads();
        s16x8 af[2][2], bfr[2][2];
        const int sa = arow & 7;
#pragma unroll
        for (int f = 0; f < 2; ++f) {
            int ra = (wm * 32 + f * 16 + arow) * 64;
            int rb = (wn * 32 + f * 16 + arow) * 64;
#pragma unroll
            for (int ks = 0; ks < 2; ++ks) {
                int q = ks * 4 + khi;
                af[ks][f]  = *(const s16x8*)&lA[ra + ((q ^ sa) << 3)];
                bfr[ks][f] = *(const s16x8*)&lB[rb + ((q ^ sa) << 3)];
            }
        }
#pragma unroll
        for (int ks = 0; ks < 2; ++ks)
#pragma unroll
            for (int i = 0; i < 2; ++i)
#pragma unroll
                for (int jj = 0; jj < 2; ++jj)
                    acc[i][jj] = __builtin_amdgcn_mfma_f32_16x16x32_bf16(
                        af[ks][i], bfr[ks][jj], acc[i][jj], 0, 0, 0);
        __syncthreads();
    }

#pragma unroll
    for (int i = 0; i < 2; ++i) {
        int gr0 = m0 + wm * 32 + i * 16 + khi * 4;
#pragma unroll
        for (int jj = 0; jj < 2; ++jj) {
            int gc = n0 + wn * 32 + jj * 16 + arow;
            if (gc >= 85) continue;
            float bb = bias[gc];
#pragma unroll
            for (int r = 0; r < 4; ++r)
                D[(size_t)(gr0 + r) * 85 + gc] = acc[i][jj][r] + bb;
        }
    }
}

extern "C" void kernel_launch(void* const* d_in, const int* in_sizes, int n_in,
                              void* d_out, int out_size, void* d_ws, size_t ws_size,
                              hipStream_t stream) {
    const float* x          = (const float*)d_in[0];
    const int*   idx        = (const int*)d_in[1];
    const float* stem_w     = (const float*)d_in[2];
    const float* stem_b     = (const float*)d_in[3];
    const float* cls_conv_w = (const float*)d_in[4];
    const float* cls_conv_b = (const float*)d_in[5];
    const float* cls_pred_w = (const float*)d_in[8];
    const float* cls_pred_b = (const float*)d_in[9];
    const float* reg_conv_w = (const float*)d_in[6];
    const float* reg_conv_b = (const float*)d_in[7];
    const float* reg_pred_w = (const float*)d_in[10];
    const float* reg_pred_b = (const float*)d_in[11];
    const float* obj_pred_w = (const float*)d_in[12];
    const float* obj_pred_b = (const float*)d_in[13];
    float* out = (float*)d_out;
    char* ws = (char*)d_ws;

    // ws layout (xT slot removed)
    u16*  stem   = (u16*)(ws);                    // 26,214,400 (NHWC bf16)
    u16*  feat   = (u16*)(ws + 26214400);         // 16,777,216
    u16*  Wc     = (u16*)(ws + 42991616);         // 2,359,296
    u16*  Wf     = (u16*)(ws + 45350912);         // 131,072
    u16*  Wsb    = (u16*)(ws + 45481984);         // 131,072
    int*  rowoff = (int*)(ws + 45613056);         // 589,824
    u16*  zpage  = (u16*)(ws + 46202880);         // 512 B
    float* bc    = (float*)(ws + 46203392);       // 2048
    float* bp    = (float*)(ws + 46205440);       // 512

    fused_pre<<<1185, 256, 0, stream>>>(idx, stem_w,
                                        cls_conv_w, cls_conv_b, reg_conv_w, reg_conv_b,
                                        cls_pred_w, cls_pred_b, reg_pred_w, reg_pred_b,
                                        obj_pred_w, obj_pred_b,
                                        Wsb, Wc, Wf, rowoff, bc, bp, zpage);
    // K1: stem = silu(x^T @ stem_w^T + b) -> NHWC bf16 [51200][256], transpose fused
    gemm_stem<<<dim3(400, 4), 256, 0, stream>>>(x, Wsb, stem_b, stem);
    // K3 fused gather+conv: feat = silu(gather(stem) @ Wc^T + bc)  [16384][512]
    gemm_conv<<<dim3(128, 8), 256, 0, stream>>>(stem, rowoff, zpage, Wc, bc, feat);
    // K4: out[n][p<85] = feat @ Wf^T + bp  (f32 store)
    gemm_pred<<<dim3(256, 2), 256, 0, stream>>>(feat, Wf, bp, out);
}